// Round 2
// baseline (4387.072 us; speedup 1.0000x reference)
//
#include <hip/hip_runtime.h>
#include <hip/hip_bf16.h>

#define N_NODES 100000
#define D_IN 128
#define D_H 256
#define D_E 64
#define MT 32  // nodes per GEMM block

typedef __attribute__((ext_vector_type(8))) short short8;
typedef __attribute__((ext_vector_type(4))) float floatx4;

__device__ inline unsigned short f2bf(float f) {
    union { float f; unsigned u; } v; v.f = f;
    unsigned r = v.u + 0x7FFF + ((v.u >> 16) & 1);
    return (unsigned short)(r >> 16);
}

#define MFMA16(a, b, c) __builtin_amdgcn_mfma_f32_16x16x32_bf16((a), (b), (c), 0, 0, 0)

// ---------------- weight pre-pack to bf16 ----------------
// W1b [256][256]: k<128 = Wl1[o][k], k>=128 = Wr1[o][k-128]
// W2b [128][256]: o<64  = Wl2[o],     o>=64  = Wr2[o-64]
// F1b [256][64] = fc1_W ; F2b [128][256] = fc2_W
__global__ void convert_weights(const float* __restrict__ Wl1, const float* __restrict__ Wr1,
                                const float* __restrict__ Wl2, const float* __restrict__ Wr2,
                                const float* __restrict__ fc1W, const float* __restrict__ fc2W,
                                unsigned short* __restrict__ W1b, unsigned short* __restrict__ W2b,
                                unsigned short* __restrict__ F1b, unsigned short* __restrict__ F2b) {
    int idx = blockIdx.x * blockDim.x + threadIdx.x;
    if (idx < 65536) {
        int o = idx >> 8, k = idx & 255;
        float v = (k < 128) ? Wl1[o * 128 + k] : Wr1[o * 128 + (k - 128)];
        W1b[idx] = f2bf(v);
    } else if (idx < 98304) {
        int i = idx - 65536; int o = i >> 8, k = i & 255;
        float v = (o < 64) ? Wl2[o * 256 + k] : Wr2[(o - 64) * 256 + k];
        W2b[i] = f2bf(v);
    } else if (idx < 114688) {
        int i = idx - 98304;
        F1b[i] = f2bf(fc1W[i]);
    } else if (idx < 147456) {
        int i = idx - 114688;
        F2b[i] = f2bf(fc2W[i]);
    }
}

// ---------------- scatter kernels ----------------

__global__ void deg_kernel(const int* __restrict__ dst, float* __restrict__ deg, int E) {
    int e = blockIdx.x * blockDim.x + threadIdx.x;
    if (e >= E) return;
    unsafeAtomicAdd(&deg[dst[e]], 1.0f);
}

// thread per (edge, float4-group); D_IN=128 -> 32 groups
__global__ void scatter_x_kernel(const float4* __restrict__ x4,
                                 const int* __restrict__ src,
                                 const int* __restrict__ dst,
                                 float* __restrict__ agg, long long total) {
    long long gid = (long long)blockIdx.x * blockDim.x + threadIdx.x;
    if (gid >= total) return;
    int e = (int)(gid >> 5);
    int f4 = (int)(gid & 31);
    int s = src[e], d = dst[e];
    float4 v = x4[(long long)s * 32 + f4];
    float* p = agg + (long long)d * D_IN + f4 * 4;
    unsafeAtomicAdd(p + 0, v.x);
    unsafeAtomicAdd(p + 1, v.y);
    unsafeAtomicAdd(p + 2, v.z);
    unsafeAtomicAdd(p + 3, v.w);
}

// thread per (edge, float4-group); D_E=64 -> 16 groups
__global__ void scatter_z_kernel(const float4* __restrict__ z4,
                                 const int* __restrict__ src,
                                 const int* __restrict__ dst,
                                 float* __restrict__ agg, long long total) {
    long long gid = (long long)blockIdx.x * blockDim.x + threadIdx.x;
    if (gid >= total) return;
    int e = (int)(gid >> 4);
    int f4 = (int)(gid & 15);
    int s = src[e], d = dst[e];
    float4 v = z4[(long long)s * 16 + f4];
    float* p = agg + (long long)d * D_E + f4 * 4;
    unsafeAtomicAdd(p + 0, v.x);
    unsafeAtomicAdd(p + 1, v.y);
    unsafeAtomicAdd(p + 2, v.z);
    unsafeAtomicAdd(p + 3, v.w);
}

// ---------------- layer1 fused MFMA ----------------
// per block (32 nodes): A=[mean|x] (K=256) -> h=relu(A@W1b^T+b) (N=256) in LDS
//                       -> [z2|r2] = h@W2b^T (N=128, K=256)
// r2 written directly into embOut (d_out emb region)
__global__ __launch_bounds__(256) void layer1_mfma(
        const float* __restrict__ x, const float* __restrict__ agg1,
        const float* __restrict__ deg,
        const unsigned short* __restrict__ W1b, const float* __restrict__ bl1,
        const unsigned short* __restrict__ W2b,
        float* __restrict__ z2, float* __restrict__ embOut) {
    __shared__ unsigned short sA[MT][264];  // +8 pad -> 2-way bank alias (free)
    __shared__ unsigned short sH[MT][264];
    __shared__ float srdeg[MT];
    const int tid = threadIdx.x;
    const int node0 = blockIdx.x * MT;

    if (tid < MT) srdeg[tid] = 1.0f / fmaxf(deg[node0 + tid], 1.0f);
    __syncthreads();

    for (int i = tid; i < MT * 128; i += 256) {
        int n = i >> 7, k = i & 127;
        long long row = (long long)(node0 + n) * D_IN;
        sA[n][k]       = f2bf(agg1[row + k] * srdeg[n]);
        sA[n][128 + k] = f2bf(x[row + k]);
    }
    __syncthreads();

    const int wave = tid >> 6, lane = tid & 63;
    const int col = lane & 15, quad = lane >> 4;

    // -------- phase A: h = relu(A @ W1b^T + bl1), N=256 --------
    short8 afr[2][8];
#pragma unroll
    for (int mt = 0; mt < 2; mt++)
#pragma unroll
        for (int ks = 0; ks < 8; ks++)
            afr[mt][ks] = *(const short8*)&sA[mt * 16 + col][ks * 32 + quad * 8];

    floatx4 acc[2][4];
    const floatx4 zero = {0.f, 0.f, 0.f, 0.f};
#pragma unroll
    for (int mt = 0; mt < 2; mt++)
#pragma unroll
        for (int nt = 0; nt < 4; nt++) acc[mt][nt] = zero;

#pragma unroll
    for (int nt = 0; nt < 4; nt++) {
        const unsigned short* wrow = W1b + ((wave * 4 + nt) * 16 + col) * 256;
#pragma unroll
        for (int ks = 0; ks < 8; ks++) {
            short8 b = *(const short8*)(wrow + ks * 32 + quad * 8);
            acc[0][nt] = MFMA16(afr[0][ks], b, acc[0][nt]);
            acc[1][nt] = MFMA16(afr[1][ks], b, acc[1][nt]);
        }
    }

#pragma unroll
    for (int nt = 0; nt < 4; nt++) {
        int out = (wave * 4 + nt) * 16 + col;
        float bias = bl1[out];
#pragma unroll
        for (int mt = 0; mt < 2; mt++)
#pragma unroll
            for (int r = 0; r < 4; r++)
                sH[mt * 16 + quad * 4 + r][out] = f2bf(fmaxf(acc[mt][nt][r] + bias, 0.f));
    }
    __syncthreads();

    // -------- phase B: [z2|r2] = h @ W2b^T, N=128, K=256 --------
    short8 hfr[2][8];
#pragma unroll
    for (int mt = 0; mt < 2; mt++)
#pragma unroll
        for (int ks = 0; ks < 8; ks++)
            hfr[mt][ks] = *(const short8*)&sH[mt * 16 + col][ks * 32 + quad * 8];

    floatx4 acc2[2][2];
#pragma unroll
    for (int mt = 0; mt < 2; mt++)
#pragma unroll
        for (int nt = 0; nt < 2; nt++) acc2[mt][nt] = zero;

#pragma unroll
    for (int nt = 0; nt < 2; nt++) {
        const unsigned short* wrow = W2b + ((wave * 2 + nt) * 16 + col) * 256;
#pragma unroll
        for (int ks = 0; ks < 8; ks++) {
            short8 b = *(const short8*)(wrow + ks * 32 + quad * 8);
            acc2[0][nt] = MFMA16(hfr[0][ks], b, acc2[0][nt]);
            acc2[1][nt] = MFMA16(hfr[1][ks], b, acc2[1][nt]);
        }
    }

#pragma unroll
    for (int nt = 0; nt < 2; nt++) {
        int out = (wave * 2 + nt) * 16 + col;
#pragma unroll
        for (int mt = 0; mt < 2; mt++)
#pragma unroll
            for (int r = 0; r < 4; r++) {
                int node = node0 + mt * 16 + quad * 4 + r;
                float v = acc2[mt][nt][r];
                if (out < 64) z2[(long long)node * D_E + out] = v;
                else          embOut[(long long)node * D_E + (out - 64)] = v;
            }
    }
}

// emb = aggz/deg + bl2 + r2(already in emb buffer)  -- in-place elementwise
__global__ void emb_kernel(const float4* __restrict__ aggz4,
                           const float* __restrict__ deg,
                           const float4* __restrict__ bl24,
                           float4* __restrict__ emb4, int total4) {
    int gid = blockIdx.x * blockDim.x + threadIdx.x;
    if (gid >= total4) return;
    int n = gid >> 4, f4 = gid & 15;
    float rd = 1.0f / fmaxf(deg[n], 1.0f);
    float4 a = aggz4[gid], b = bl24[f4], e = emb4[gid];
    e.x += a.x * rd + b.x;
    e.y += a.y * rd + b.y;
    e.z += a.z * rd + b.z;
    e.w += a.w * rd + b.w;
    emb4[gid] = e;
}

// ---------------- decoder fused MFMA ----------------
// hid = relu(emb @ F1b^T + fc1b) (N=256, K=64) in LDS -> recon = hid @ F2b^T + fc2b
__global__ __launch_bounds__(256) void decoder_mfma(
        const float* __restrict__ emb,
        const unsigned short* __restrict__ F1b, const float* __restrict__ fc1b,
        const unsigned short* __restrict__ F2b, const float* __restrict__ fc2b,
        float* __restrict__ recon) {
    __shared__ unsigned short sE[MT][72];   // 64 + 8 pad
    __shared__ unsigned short sH[MT][264];
    const int tid = threadIdx.x;
    const int node0 = blockIdx.x * MT;

    for (int i = tid; i < MT * 64; i += 256) {
        int n = i >> 6, k = i & 63;
        sE[n][k] = f2bf(emb[(long long)(node0 + n) * D_E + k]);
    }
    __syncthreads();

    const int wave = tid >> 6, lane = tid & 63;
    const int col = lane & 15, quad = lane >> 4;

    // -------- phase A: hid, K=64 (2 k-steps), N=256 --------
    short8 afr[2][2];
#pragma unroll
    for (int mt = 0; mt < 2; mt++)
#pragma unroll
        for (int ks = 0; ks < 2; ks++)
            afr[mt][ks] = *(const short8*)&sE[mt * 16 + col][ks * 32 + quad * 8];

    floatx4 acc[2][4];
    const floatx4 zero = {0.f, 0.f, 0.f, 0.f};
#pragma unroll
    for (int mt = 0; mt < 2; mt++)
#pragma unroll
        for (int nt = 0; nt < 4; nt++) acc[mt][nt] = zero;

#pragma unroll
    for (int nt = 0; nt < 4; nt++) {
        const unsigned short* wrow = F1b + ((wave * 4 + nt) * 16 + col) * 64;
#pragma unroll
        for (int ks = 0; ks < 2; ks++) {
            short8 b = *(const short8*)(wrow + ks * 32 + quad * 8);
            acc[0][nt] = MFMA16(afr[0][ks], b, acc[0][nt]);
            acc[1][nt] = MFMA16(afr[1][ks], b, acc[1][nt]);
        }
    }

#pragma unroll
    for (int nt = 0; nt < 4; nt++) {
        int out = (wave * 4 + nt) * 16 + col;
        float bias = fc1b[out];
#pragma unroll
        for (int mt = 0; mt < 2; mt++)
#pragma unroll
            for (int r = 0; r < 4; r++)
                sH[mt * 16 + quad * 4 + r][out] = f2bf(fmaxf(acc[mt][nt][r] + bias, 0.f));
    }
    __syncthreads();

    // -------- phase B: recon, N=128, K=256 --------
    short8 hfr[2][8];
#pragma unroll
    for (int mt = 0; mt < 2; mt++)
#pragma unroll
        for (int ks = 0; ks < 8; ks++)
            hfr[mt][ks] = *(const short8*)&sH[mt * 16 + col][ks * 32 + quad * 8];

    floatx4 acc2[2][2];
#pragma unroll
    for (int mt = 0; mt < 2; mt++)
#pragma unroll
        for (int nt = 0; nt < 2; nt++) acc2[mt][nt] = zero;

#pragma unroll
    for (int nt = 0; nt < 2; nt++) {
        const unsigned short* wrow = F2b + ((wave * 2 + nt) * 16 + col) * 256;
#pragma unroll
        for (int ks = 0; ks < 8; ks++) {
            short8 b = *(const short8*)(wrow + ks * 32 + quad * 8);
            acc2[0][nt] = MFMA16(hfr[0][ks], b, acc2[0][nt]);
            acc2[1][nt] = MFMA16(hfr[1][ks], b, acc2[1][nt]);
        }
    }

#pragma unroll
    for (int nt = 0; nt < 2; nt++) {
        int out = (wave * 2 + nt) * 16 + col;
        float bias = fc2b[out];
#pragma unroll
        for (int mt = 0; mt < 2; mt++)
#pragma unroll
            for (int r = 0; r < 4; r++) {
                int node = node0 + mt * 16 + quad * 4 + r;
                recon[(long long)node * D_IN + out] = acc2[mt][nt][r] + bias;
            }
    }
}

extern "C" void kernel_launch(void* const* d_in, const int* in_sizes, int n_in,
                              void* d_out, int out_size, void* d_ws, size_t ws_size,
                              hipStream_t stream) {
    const float* x    = (const float*)d_in[0];
    const int*   ei   = (const int*)d_in[1];
    const int E = in_sizes[1] / 2;
    const int* src = ei;
    const int* dst = ei + E;
    const float* Wl1  = (const float*)d_in[2];
    const float* bl1  = (const float*)d_in[3];
    const float* Wr1  = (const float*)d_in[4];
    const float* Wl2  = (const float*)d_in[5];
    const float* bl2  = (const float*)d_in[6];
    const float* Wr2  = (const float*)d_in[7];
    const float* fc1W = (const float*)d_in[8];
    const float* fc1b = (const float*)d_in[9];
    const float* fc2W = (const float*)d_in[10];
    const float* fc2b = (const float*)d_in[11];

    float* out   = (float*)d_out;
    float* emb   = out;                           // N*64
    float* recon = out + (size_t)N_NODES * D_E;   // N*128

    // workspace layout
    char* ws = (char*)d_ws;
    float* agg1 = (float*)(ws);                         // 51,200,000 B
    float* z2   = (float*)(ws + 51200000);              // 25,600,000 B
    float* aggz = (float*)(ws + 76800000);              // 25,600,000 B
    float* deg  = (float*)(ws + 102400000);             //    400,000 B
    unsigned short* W1b = (unsigned short*)(ws + 102800000);  // 131,072 B
    unsigned short* W2b = (unsigned short*)(ws + 102931072);  //  65,536 B
    unsigned short* F1b = (unsigned short*)(ws + 102996608);  //  32,768 B
    unsigned short* F2b = (unsigned short*)(ws + 103029376);  //  65,536 B
    // end: 103,094,912 B (< round-1 proven 128.4 MB)

    hipMemsetAsync(agg1, 0, (size_t)N_NODES * D_IN * sizeof(float), stream);
    hipMemsetAsync(aggz, 0, (size_t)N_NODES * D_E * sizeof(float), stream);
    hipMemsetAsync(deg,  0, (size_t)N_NODES * sizeof(float), stream);

    convert_weights<<<(147456 + 255) / 256, 256, 0, stream>>>(
        Wl1, Wr1, Wl2, Wr2, fc1W, fc2W, W1b, W2b, F1b, F2b);

    deg_kernel<<<(E + 255) / 256, 256, 0, stream>>>(dst, deg, E);

    long long tot1 = (long long)E * 32;
    scatter_x_kernel<<<(int)((tot1 + 255) / 256), 256, 0, stream>>>(
        (const float4*)x, src, dst, agg1, tot1);

    layer1_mfma<<<N_NODES / MT, 256, 0, stream>>>(x, agg1, deg, W1b, bl1, W2b, z2, emb);

    long long tot2 = (long long)E * 16;
    scatter_z_kernel<<<(int)((tot2 + 255) / 256), 256, 0, stream>>>(
        (const float4*)z2, src, dst, aggz, tot2);

    emb_kernel<<<(N_NODES * 16 + 255) / 256, 256, 0, stream>>>(
        (const float4*)aggz, deg, (const float4*)bl2, (float4*)emb, N_NODES * 16);

    decoder_mfma<<<N_NODES / MT, 256, 0, stream>>>(emb, F1b, fc1b, F2b, fc2b, recon);
}

// Round 3
// 600.899 us; speedup vs baseline: 7.3008x; 7.3008x over previous
//
#include <hip/hip_runtime.h>
#include <hip/hip_bf16.h>

#define N_NODES 100000
#define D_IN 128
#define D_H 256
#define D_E 64
#define MT 32        // nodes per GEMM block
#define SCAN_B 1024  // scan block size

typedef __attribute__((ext_vector_type(8))) short short8;
typedef __attribute__((ext_vector_type(4))) float floatx4;

__device__ inline unsigned short f2bf(float f) {
    union { float f; unsigned u; } v; v.f = f;
    unsigned r = v.u + 0x7FFF + ((v.u >> 16) & 1);
    return (unsigned short)(r >> 16);
}

#define MFMA16(a, b, c) __builtin_amdgcn_mfma_f32_16x16x32_bf16((a), (b), (c), 0, 0, 0)

// ---------------- weight pre-pack to bf16 ----------------
__global__ void convert_weights(const float* __restrict__ Wl1, const float* __restrict__ Wr1,
                                const float* __restrict__ Wl2, const float* __restrict__ Wr2,
                                const float* __restrict__ fc1W, const float* __restrict__ fc2W,
                                unsigned short* __restrict__ W1b, unsigned short* __restrict__ W2b,
                                unsigned short* __restrict__ F1b, unsigned short* __restrict__ F2b) {
    int idx = blockIdx.x * blockDim.x + threadIdx.x;
    if (idx < 65536) {
        int o = idx >> 8, k = idx & 255;
        float v = (k < 128) ? Wl1[o * 128 + k] : Wr1[o * 128 + (k - 128)];
        W1b[idx] = f2bf(v);
    } else if (idx < 98304) {
        int i = idx - 65536; int o = i >> 8, k = i & 255;
        float v = (o < 64) ? Wl2[o * 256 + k] : Wr2[(o - 64) * 256 + k];
        W2b[i] = f2bf(v);
    } else if (idx < 114688) {
        int i = idx - 98304;
        F1b[i] = f2bf(fc1W[i]);
    } else if (idx < 147456) {
        int i = idx - 114688;
        F2b[i] = f2bf(fc2W[i]);
    }
}

// ---------------- counting sort of edges by dst ----------------

__global__ void hist_kernel(const int* __restrict__ dst, int* __restrict__ degI, int E) {
    int e = blockIdx.x * blockDim.x + threadIdx.x;
    if (e >= E) return;
    atomicAdd(&degI[dst[e]], 1);
}

// exclusive scan, 3-phase
__global__ void scan_block(const int* __restrict__ degI, int* __restrict__ offs,
                           int* __restrict__ bsum, int N) {
    __shared__ int s[SCAN_B];
    int tid = threadIdx.x;
    int gid = blockIdx.x * SCAN_B + tid;
    int v = (gid < N) ? degI[gid] : 0;
    s[tid] = v;
    __syncthreads();
    for (int off = 1; off < SCAN_B; off <<= 1) {
        int t = (tid >= off) ? s[tid - off] : 0;
        __syncthreads();
        s[tid] += t;
        __syncthreads();
    }
    if (gid < N) offs[gid] = s[tid] - v;
    if (tid == SCAN_B - 1) bsum[blockIdx.x] = s[tid];
}

__global__ void scan_bsum(int* __restrict__ bsum, int nb) {
    __shared__ int s[128];
    int tid = threadIdx.x;
    int v = (tid < nb) ? bsum[tid] : 0;
    s[tid] = v;
    __syncthreads();
    for (int off = 1; off < 128; off <<= 1) {
        int t = (tid >= off) ? s[tid - off] : 0;
        __syncthreads();
        s[tid] += t;
        __syncthreads();
    }
    if (tid < nb) bsum[tid] = s[tid] - v;
}

__global__ void scan_add(int* __restrict__ offs, const int* __restrict__ bsum, int N) {
    int gid = blockIdx.x * SCAN_B + threadIdx.x;
    if (gid < N) offs[gid] += bsum[blockIdx.x];
}

__global__ void reorder_kernel(const int* __restrict__ src, const int* __restrict__ dst,
                               const int* __restrict__ offs, int* __restrict__ cursor,
                               int* __restrict__ srcS, int E) {
    int e = blockIdx.x * blockDim.x + threadIdx.x;
    if (e >= E) return;
    int d = dst[e];
    int pos = offs[d] + atomicAdd(&cursor[d], 1);
    srcS[pos] = src[e];
}

// ---------------- segment-sum gathers (atomic-free) ----------------

// one wave per node; lane covers 2 floats (D_IN=128); writes mean = agg/deg
__global__ __launch_bounds__(256) void gather_mean(
        const float2* __restrict__ x2, const int* __restrict__ srcS,
        const int* __restrict__ offs, const int* __restrict__ degI,
        float2* __restrict__ mean2) {
    const int wave = threadIdx.x >> 6, lane = threadIdx.x & 63;
    const int n = blockIdx.x * 4 + wave;
    if (n >= N_NODES) return;
    const int start = offs[n], cnt = degI[n];
    const int* sp = srcS + start;
    float2 a0 = {0.f, 0.f}, a1 = {0.f, 0.f}, a2 = {0.f, 0.f}, a3 = {0.f, 0.f};
    int j = 0;
    for (; j + 4 <= cnt; j += 4) {
        int s0 = sp[j], s1 = sp[j + 1], s2 = sp[j + 2], s3 = sp[j + 3];
        float2 v0 = x2[(long long)s0 * 64 + lane];
        float2 v1 = x2[(long long)s1 * 64 + lane];
        float2 v2 = x2[(long long)s2 * 64 + lane];
        float2 v3 = x2[(long long)s3 * 64 + lane];
        a0.x += v0.x; a0.y += v0.y;
        a1.x += v1.x; a1.y += v1.y;
        a2.x += v2.x; a2.y += v2.y;
        a3.x += v3.x; a3.y += v3.y;
    }
    for (; j < cnt; j++) {
        int s0 = sp[j];
        float2 v0 = x2[(long long)s0 * 64 + lane];
        a0.x += v0.x; a0.y += v0.y;
    }
    float rd = 1.0f / fmaxf((float)cnt, 1.0f);
    float2 m;
    m.x = (a0.x + a1.x + a2.x + a3.x) * rd;
    m.y = (a0.y + a1.y + a2.y + a3.y) * rd;
    mean2[(long long)n * 64 + lane] = m;
}

// one wave per node; lane = feature (D_E=64); emb += agg/deg + bl2 (emb holds r2)
__global__ __launch_bounds__(256) void gather_emb(
        const float* __restrict__ z2, const int* __restrict__ srcS,
        const int* __restrict__ offs, const int* __restrict__ degI,
        const float* __restrict__ bl2, float* __restrict__ emb) {
    const int wave = threadIdx.x >> 6, lane = threadIdx.x & 63;
    const int n = blockIdx.x * 4 + wave;
    if (n >= N_NODES) return;
    const int start = offs[n], cnt = degI[n];
    const int* sp = srcS + start;
    float a0 = 0.f, a1 = 0.f, a2 = 0.f, a3 = 0.f;
    int j = 0;
    for (; j + 4 <= cnt; j += 4) {
        int s0 = sp[j], s1 = sp[j + 1], s2 = sp[j + 2], s3 = sp[j + 3];
        a0 += z2[(long long)s0 * 64 + lane];
        a1 += z2[(long long)s1 * 64 + lane];
        a2 += z2[(long long)s2 * 64 + lane];
        a3 += z2[(long long)s3 * 64 + lane];
    }
    for (; j < cnt; j++) a0 += z2[(long long)sp[j] * 64 + lane];
    float rd = 1.0f / fmaxf((float)cnt, 1.0f);
    long long idx = (long long)n * 64 + lane;
    emb[idx] = (a0 + a1 + a2 + a3) * rd + bl2[lane] + emb[idx];
}

// ---------------- layer1 fused MFMA ----------------
__global__ __launch_bounds__(256) void layer1_mfma(
        const float* __restrict__ x, const float* __restrict__ mean,
        const unsigned short* __restrict__ W1b, const float* __restrict__ bl1,
        const unsigned short* __restrict__ W2b,
        float* __restrict__ z2, float* __restrict__ embOut) {
    __shared__ unsigned short sA[MT][264];
    __shared__ unsigned short sH[MT][264];
    const int tid = threadIdx.x;
    const int node0 = blockIdx.x * MT;

    for (int i = tid; i < MT * 128; i += 256) {
        int n = i >> 7, k = i & 127;
        long long row = (long long)(node0 + n) * D_IN;
        sA[n][k]       = f2bf(mean[row + k]);
        sA[n][128 + k] = f2bf(x[row + k]);
    }
    __syncthreads();

    const int wave = tid >> 6, lane = tid & 63;
    const int col = lane & 15, quad = lane >> 4;

    short8 afr[2][8];
#pragma unroll
    for (int mt = 0; mt < 2; mt++)
#pragma unroll
        for (int ks = 0; ks < 8; ks++)
            afr[mt][ks] = *(const short8*)&sA[mt * 16 + col][ks * 32 + quad * 8];

    floatx4 acc[2][4];
    const floatx4 zero = {0.f, 0.f, 0.f, 0.f};
#pragma unroll
    for (int mt = 0; mt < 2; mt++)
#pragma unroll
        for (int nt = 0; nt < 4; nt++) acc[mt][nt] = zero;

#pragma unroll
    for (int nt = 0; nt < 4; nt++) {
        const unsigned short* wrow = W1b + ((wave * 4 + nt) * 16 + col) * 256;
#pragma unroll
        for (int ks = 0; ks < 8; ks++) {
            short8 b = *(const short8*)(wrow + ks * 32 + quad * 8);
            acc[0][nt] = MFMA16(afr[0][ks], b, acc[0][nt]);
            acc[1][nt] = MFMA16(afr[1][ks], b, acc[1][nt]);
        }
    }

#pragma unroll
    for (int nt = 0; nt < 4; nt++) {
        int out = (wave * 4 + nt) * 16 + col;
        float bias = bl1[out];
#pragma unroll
        for (int mt = 0; mt < 2; mt++)
#pragma unroll
            for (int r = 0; r < 4; r++)
                sH[mt * 16 + quad * 4 + r][out] = f2bf(fmaxf(acc[mt][nt][r] + bias, 0.f));
    }
    __syncthreads();

    short8 hfr[2][8];
#pragma unroll
    for (int mt = 0; mt < 2; mt++)
#pragma unroll
        for (int ks = 0; ks < 8; ks++)
            hfr[mt][ks] = *(const short8*)&sH[mt * 16 + col][ks * 32 + quad * 8];

    floatx4 acc2[2][2];
#pragma unroll
    for (int mt = 0; mt < 2; mt++)
#pragma unroll
        for (int nt = 0; nt < 2; nt++) acc2[mt][nt] = zero;

#pragma unroll
    for (int nt = 0; nt < 2; nt++) {
        const unsigned short* wrow = W2b + ((wave * 2 + nt) * 16 + col) * 256;
#pragma unroll
        for (int ks = 0; ks < 8; ks++) {
            short8 b = *(const short8*)(wrow + ks * 32 + quad * 8);
            acc2[0][nt] = MFMA16(hfr[0][ks], b, acc2[0][nt]);
            acc2[1][nt] = MFMA16(hfr[1][ks], b, acc2[1][nt]);
        }
    }

#pragma unroll
    for (int nt = 0; nt < 2; nt++) {
        int out = (wave * 2 + nt) * 16 + col;
#pragma unroll
        for (int mt = 0; mt < 2; mt++)
#pragma unroll
            for (int r = 0; r < 4; r++) {
                int node = node0 + mt * 16 + quad * 4 + r;
                float v = acc2[mt][nt][r];
                if (out < 64) z2[(long long)node * D_E + out] = v;
                else          embOut[(long long)node * D_E + (out - 64)] = v;
            }
    }
}

// ---------------- decoder fused MFMA ----------------
__global__ __launch_bounds__(256) void decoder_mfma(
        const float* __restrict__ emb,
        const unsigned short* __restrict__ F1b, const float* __restrict__ fc1b,
        const unsigned short* __restrict__ F2b, const float* __restrict__ fc2b,
        float* __restrict__ recon) {
    __shared__ unsigned short sE[MT][72];
    __shared__ unsigned short sH[MT][264];
    const int tid = threadIdx.x;
    const int node0 = blockIdx.x * MT;

    for (int i = tid; i < MT * 64; i += 256) {
        int n = i >> 6, k = i & 63;
        sE[n][k] = f2bf(emb[(long long)(node0 + n) * D_E + k]);
    }
    __syncthreads();

    const int wave = tid >> 6, lane = tid & 63;
    const int col = lane & 15, quad = lane >> 4;

    short8 afr[2][2];
#pragma unroll
    for (int mt = 0; mt < 2; mt++)
#pragma unroll
        for (int ks = 0; ks < 2; ks++)
            afr[mt][ks] = *(const short8*)&sE[mt * 16 + col][ks * 32 + quad * 8];

    floatx4 acc[2][4];
    const floatx4 zero = {0.f, 0.f, 0.f, 0.f};
#pragma unroll
    for (int mt = 0; mt < 2; mt++)
#pragma unroll
        for (int nt = 0; nt < 4; nt++) acc[mt][nt] = zero;

#pragma unroll
    for (int nt = 0; nt < 4; nt++) {
        const unsigned short* wrow = F1b + ((wave * 4 + nt) * 16 + col) * 64;
#pragma unroll
        for (int ks = 0; ks < 2; ks++) {
            short8 b = *(const short8*)(wrow + ks * 32 + quad * 8);
            acc[0][nt] = MFMA16(afr[0][ks], b, acc[0][nt]);
            acc[1][nt] = MFMA16(afr[1][ks], b, acc[1][nt]);
        }
    }

#pragma unroll
    for (int nt = 0; nt < 4; nt++) {
        int out = (wave * 4 + nt) * 16 + col;
        float bias = fc1b[out];
#pragma unroll
        for (int mt = 0; mt < 2; mt++)
#pragma unroll
            for (int r = 0; r < 4; r++)
                sH[mt * 16 + quad * 4 + r][out] = f2bf(fmaxf(acc[mt][nt][r] + bias, 0.f));
    }
    __syncthreads();

    short8 hfr[2][8];
#pragma unroll
    for (int mt = 0; mt < 2; mt++)
#pragma unroll
        for (int ks = 0; ks < 8; ks++)
            hfr[mt][ks] = *(const short8*)&sH[mt * 16 + col][ks * 32 + quad * 8];

    floatx4 acc2[2][2];
#pragma unroll
    for (int mt = 0; mt < 2; mt++)
#pragma unroll
        for (int nt = 0; nt < 2; nt++) acc2[mt][nt] = zero;

#pragma unroll
    for (int nt = 0; nt < 2; nt++) {
        const unsigned short* wrow = F2b + ((wave * 2 + nt) * 16 + col) * 256;
#pragma unroll
        for (int ks = 0; ks < 8; ks++) {
            short8 b = *(const short8*)(wrow + ks * 32 + quad * 8);
            acc2[0][nt] = MFMA16(hfr[0][ks], b, acc2[0][nt]);
            acc2[1][nt] = MFMA16(hfr[1][ks], b, acc2[1][nt]);
        }
    }

#pragma unroll
    for (int nt = 0; nt < 2; nt++) {
        int out = (wave * 2 + nt) * 16 + col;
        float bias = fc2b[out];
#pragma unroll
        for (int mt = 0; mt < 2; mt++)
#pragma unroll
            for (int r = 0; r < 4; r++) {
                int node = node0 + mt * 16 + quad * 4 + r;
                recon[(long long)node * D_IN + out] = acc2[mt][nt][r] + bias;
            }
    }
}

extern "C" void kernel_launch(void* const* d_in, const int* in_sizes, int n_in,
                              void* d_out, int out_size, void* d_ws, size_t ws_size,
                              hipStream_t stream) {
    const float* x    = (const float*)d_in[0];
    const int*   ei   = (const int*)d_in[1];
    const int E = in_sizes[1] / 2;
    const int* src = ei;
    const int* dst = ei + E;
    const float* Wl1  = (const float*)d_in[2];
    const float* bl1  = (const float*)d_in[3];
    const float* Wr1  = (const float*)d_in[4];
    const float* Wl2  = (const float*)d_in[5];
    const float* bl2  = (const float*)d_in[6];
    const float* Wr2  = (const float*)d_in[7];
    const float* fc1W = (const float*)d_in[8];
    const float* fc1b = (const float*)d_in[9];
    const float* fc2W = (const float*)d_in[10];
    const float* fc2b = (const float*)d_in[11];

    float* out   = (float*)d_out;
    float* emb   = out;                           // N*64
    float* recon = out + (size_t)N_NODES * D_E;   // N*128

    // workspace layout (all offsets 512-aligned)
    char* ws = (char*)d_ws;
    float* mean   = (float*)(ws);                        // 51,200,000 B
    float* z2     = (float*)(ws + 51200000);             // 25,600,000 B
    int*   degI   = (int*)  (ws + 76800000);             //    400,000 B
    int*   offs   = (int*)  (ws + 77200384);             //    400,000 B
    int*   cursor = (int*)  (ws + 77600768);             //    400,000 B
    int*   bsum   = (int*)  (ws + 78001152);             //        512 B
    int*   srcS   = (int*)  (ws + 78001664);             //  6,400,000 B (E ints)
    unsigned short* W1b = (unsigned short*)(ws + 84401664);  // 131,072 B
    unsigned short* W2b = (unsigned short*)(ws + 84532736);  //  65,536 B
    unsigned short* F1b = (unsigned short*)(ws + 84598272);  //  32,768 B
    unsigned short* F2b = (unsigned short*)(ws + 84631040);  //  65,536 B
    // end ~84.7 MB (< 103 MB used in round 2)

    hipMemsetAsync(degI,   0, (size_t)N_NODES * sizeof(int), stream);
    hipMemsetAsync(cursor, 0, (size_t)N_NODES * sizeof(int), stream);

    convert_weights<<<(147456 + 255) / 256, 256, 0, stream>>>(
        Wl1, Wr1, Wl2, Wr2, fc1W, fc2W, W1b, W2b, F1b, F2b);

    // counting sort of edges by dst
    hist_kernel<<<(E + 255) / 256, 256, 0, stream>>>(dst, degI, E);
    const int nScanBlocks = (N_NODES + SCAN_B - 1) / SCAN_B;  // 98
    scan_block<<<nScanBlocks, SCAN_B, 0, stream>>>(degI, offs, bsum, N_NODES);
    scan_bsum<<<1, 128, 0, stream>>>(bsum, nScanBlocks);
    scan_add<<<nScanBlocks, SCAN_B, 0, stream>>>(offs, bsum, N_NODES);
    reorder_kernel<<<(E + 255) / 256, 256, 0, stream>>>(src, dst, offs, cursor, srcS, E);

    // layer 1: mean aggregation (gather) + fused GEMMs
    gather_mean<<<(N_NODES + 3) / 4, 256, 0, stream>>>(
        (const float2*)x, srcS, offs, degI, (float2*)mean);
    layer1_mfma<<<N_NODES / MT, 256, 0, stream>>>(x, mean, W1b, bl1, W2b, z2, emb);

    // layer 2: z aggregation (gather) fused with emb finalize
    gather_emb<<<(N_NODES + 3) / 4, 256, 0, stream>>>(z2, srcS, offs, degI, bl2, emb);

    // decoder
    decoder_mfma<<<N_NODES / MT, 256, 0, stream>>>(emb, F1b, fc1b, F2b, fc2b, recon);
}